// Round 7
// baseline (305.562 us; speedup 1.0000x reference)
//
#include <hip/hip_runtime.h>
#include <stdint.h>

typedef unsigned short u16;
typedef short bf16x8 __attribute__((ext_vector_type(8)));
typedef float f32x4 __attribute__((ext_vector_type(4)));
typedef float f32x16 __attribute__((ext_vector_type(16)));

#define MB (1024L*1024L)

__device__ inline u16 f2bf(float f) {
  union { float f; unsigned u; } v; v.f = f;
  unsigned r = (v.u + 0x7FFFu + ((v.u >> 16) & 1u)) >> 16;
  return (u16)r;
}

__device__ inline float bf2f(u16 u) {
  union { unsigned u; float f; } v; v.u = ((unsigned)u) << 16; return v.f;
}

__device__ inline unsigned cvtpk(float lo, float hi) {
  unsigned r;
  asm("v_cvt_pk_bf16_f32 %0, %1, %2" : "=v"(r) : "v"(lo), "v"(hi));
  return r;
}

#define GLOAD16(gptr, lptr) \
  __builtin_amdgcn_global_load_lds((__attribute__((address_space(1))) void*)(gptr), \
                                   (__attribute__((address_space(3))) void*)(lptr), 16, 0, 0)

// ---------------- transpose + convert fp32 (K,N) -> bf16 (N,K) ----------------
__global__ __launch_bounds__(256) void twconv(const float* __restrict__ W,
                                              u16* __restrict__ WT, int K, int N) {
  __shared__ float tile[32][33];
  const int nbn = N >> 5;
  const int bk = blockIdx.x / nbn;
  const int bn = blockIdx.x % nbn;
  const int tid = threadIdx.x;
  const int r = tid >> 3;
  const int c4 = (tid & 7) << 2;
  const float4 v = *(const float4*)(W + (size_t)(bk * 32 + r) * N + bn * 32 + c4);
  tile[r][c4 + 0] = v.x; tile[r][c4 + 1] = v.y;
  tile[r][c4 + 2] = v.z; tile[r][c4 + 3] = v.w;
  __syncthreads();
  ushort4 o;
  o.x = f2bf(tile[c4 + 0][r]); o.y = f2bf(tile[c4 + 1][r]);
  o.z = f2bf(tile[c4 + 2][r]); o.w = f2bf(tile[c4 + 3][r]);
  *(ushort4*)(WT + (size_t)(bn * 32 + r) * K + bk * 32 + c4) = o;
}

// ---------------- concat 3 bias vectors ----------------
__global__ __launch_bounds__(256) void concat3(const float* __restrict__ a,
                                               const float* __restrict__ b,
                                               const float* __restrict__ c,
                                               float* __restrict__ out, int n) {
  int i = blockIdx.x * 256 + threadIdx.x;
  if (i < n) { out[i] = a[i]; out[n + i] = b[i]; out[2 * n + i] = c[i]; }
}

// ---------------- LayerNorm fp32 -> bf16, D=1024, one block per row ----------------
__global__ __launch_bounds__(256) void ln_kernel(const float* __restrict__ x,
                                                 const float* __restrict__ gamma,
                                                 const float* __restrict__ beta,
                                                 u16* __restrict__ out) {
  const int row = blockIdx.x;
  const int tid = threadIdx.x;
  const float4 v = *(const float4*)(x + (size_t)row * 1024 + tid * 4);
  float s = v.x + v.y + v.z + v.w;
  float s2 = v.x * v.x + v.y * v.y + v.z * v.z + v.w * v.w;
#pragma unroll
  for (int m = 1; m < 64; m <<= 1) {
    s += __shfl_xor(s, m, 64);
    s2 += __shfl_xor(s2, m, 64);
  }
  __shared__ float red[8];
  const int w = tid >> 6;
  if ((tid & 63) == 0) { red[w] = s; red[4 + w] = s2; }
  __syncthreads();
  s = red[0] + red[1] + red[2] + red[3];
  s2 = red[4] + red[5] + red[6] + red[7];
  const float mean = s * (1.0f / 1024.0f);
  const float var = s2 * (1.0f / 1024.0f) - mean * mean;
  const float rstd = rsqrtf(var + 1e-5f);
  const float4 g = *(const float4*)(gamma + tid * 4);
  const float4 b = *(const float4*)(beta + tid * 4);
  ushort4 o;
  o.x = f2bf(g.x * (v.x - mean) * rstd + b.x);
  o.y = f2bf(g.y * (v.y - mean) * rstd + b.y);
  o.z = f2bf(g.z * (v.z - mean) * rstd + b.z);
  o.w = f2bf(g.w * (v.w - mean) * rstd + b.w);
  *(ushort4*)(out + (size_t)row * 1024 + tid * 4) = o;
}

// ---------------- GEMM: C[M,N] = A[M,K](bf16) @ BT[N,K](bf16)^T ----------------
// BK=64, dbuf, depth-2 prefetch, counted vmcnt, raw barriers, setprio; XCD-swizzled grid.
// Requires M = 4096 (nBM = 32). EPI 0: bf16=acc+bias; 1: f32=acc+bias+res; 2: bf16=gelu.
template <int EPI, int BN>
__global__ __launch_bounds__(256, (BN == 64) ? 3 : 2)
void gemm_bt(const u16* __restrict__ A, const u16* __restrict__ BT,
             const float* __restrict__ bias, const float* __restrict__ res,
             void* __restrict__ outp, int M, int N, int K) {
  constexpr int MF = (BN == 128) ? 4 : 2;
  constexpr int ACH = 4;
  constexpr int BCH = BN / 32;
  constexpr int LOADS = ACH + BCH;
  __shared__ __align__(16) u16 As[2][128 * 64];
  __shared__ __align__(16) u16 Bs[2][BN * 64];
  const int nBN = N / BN;
  const int hw = blockIdx.x;
  const int xcd = hw & 7;
  const int rr = hw >> 3;
  const int bm = xcd * 4 + rr / nBN;
  const int bn = rr % nBN;
  const int tid = threadIdx.x;
  const int lane = tid & 63;
  const int wid = tid >> 6;
  const int wm = (BN == 128) ? (wid >> 1) : wid;
  const int wn = (BN == 128) ? (wid & 1) : 0;
  const int e4 = lane >> 4;

  int abase[MF], ax[MF];
#pragma unroll
  for (int m = 0; m < MF; ++m) {
    int rowa = wm * (MF * 16) + m * 16 + (lane & 15);
    abase[m] = rowa * 64; ax[m] = rowa & 7;
  }
  int bbase[4], bx[4];
#pragma unroll
  for (int n = 0; n < 4; ++n) {
    int rowb = wn * 64 + n * 16 + (lane & 15);
    bbase[n] = rowb * 64; bx[n] = rowb & 7;
  }

  size_t ga[ACH]; int loa[ACH];
#pragma unroll
  for (int c = 0; c < ACH; ++c) {
    int idx = tid + (c << 8);
    int row = idx >> 3;
    int ch = (idx & 7) ^ (row & 7);
    ga[c] = (size_t)(bm * 128 + row) * K + (ch << 3);
    loa[c] = idx << 4;
  }
  size_t gb[BCH]; int lob[BCH];
#pragma unroll
  for (int c = 0; c < BCH; ++c) {
    int idx = tid + (c << 8);
    int row = idx >> 3;
    int ch = (idx & 7) ^ (row & 7);
    gb[c] = (size_t)(bn * BN + row) * K + (ch << 3);
    lob[c] = idx << 4;
  }

#define STAGE_G(t, bb) do { \
  _Pragma("unroll") for (int c = 0; c < ACH; ++c) \
    GLOAD16(A + ga[c] + (size_t)(t) * 64, (char*)As[bb] + loa[c]); \
  _Pragma("unroll") for (int c = 0; c < BCH; ++c) \
    GLOAD16(BT + gb[c] + (size_t)(t) * 64, (char*)Bs[bb] + lob[c]); \
} while (0)

  f32x4 acc[MF][4] = {};
  const int nt = K >> 6;

  STAGE_G(0, 0);
  STAGE_G(1, 1);

  for (int t = 0; t < nt; ++t) {
    if (t + 1 < nt) {
      asm volatile("s_waitcnt vmcnt(%0)" :: "i"(LOADS) : "memory");
    } else {
      asm volatile("s_waitcnt vmcnt(0)" ::: "memory");
    }
    __builtin_amdgcn_s_barrier();          // buf[t&1] published
    const u16* Ap = As[t & 1];
    const u16* Bp = Bs[t & 1];
    bf16x8 af[2][MF], bfr[2][4];
#pragma unroll
    for (int kk = 0; kk < 2; ++kk) {
#pragma unroll
      for (int m = 0; m < MF; ++m)
        af[kk][m] = *(const bf16x8*)(Ap + abase[m] + (((((kk << 2) | e4)) ^ ax[m]) << 3));
#pragma unroll
      for (int n = 0; n < 4; ++n)
        bfr[kk][n] = *(const bf16x8*)(Bp + bbase[n] + (((((kk << 2) | e4)) ^ bx[n]) << 3));
    }
    asm volatile("s_waitcnt lgkmcnt(0)" ::: "memory");
    __builtin_amdgcn_s_barrier();          // all waves done reading buf[t&1]
    if (t + 2 < nt) STAGE_G(t + 2, t & 1);
    __builtin_amdgcn_s_setprio(1);
#pragma unroll
    for (int kk = 0; kk < 2; ++kk)
#pragma unroll
      for (int m = 0; m < MF; ++m)
#pragma unroll
        for (int n = 0; n < 4; ++n)
          acc[m][n] = __builtin_amdgcn_mfma_f32_16x16x32_bf16(af[kk][m], bfr[kk][n], acc[m][n], 0, 0, 0);
    __builtin_amdgcn_s_setprio(0);
  }
#undef STAGE_G

  const int rbase = bm * 128 + wm * (MF * 16);
  const int cbase = bn * BN + wn * 64;
#pragma unroll
  for (int m = 0; m < MF; ++m) {
#pragma unroll
    for (int n = 0; n < 4; ++n) {
      const int col = cbase + n * 16 + (lane & 15);
      const int row0 = rbase + m * 16 + ((lane >> 4) << 2);
      const float bv = bias[col];
#pragma unroll
      for (int r = 0; r < 4; ++r) {
        const int row = row0 + r;
        float v = acc[m][n][r] + bv;
        if (EPI == 1) {
          ((float*)outp)[(size_t)row * N + col] = v + res[(size_t)row * N + col];
        } else if (EPI == 2) {
          float tt = v * (1.0f + 0.044715f * v * v);
          float sg = 1.0f / (1.0f + __expf(-1.5957691216057308f * tt));
          ((u16*)outp)[(size_t)row * N + col] = f2bf(v * sg);
        } else {
          ((u16*)outp)[(size_t)row * N + col] = f2bf(v);
        }
      }
    }
  }
}

// ---------------- causal flash attention: 4-warp blocks, 1 chunk each, LPT grid ----------------
// QKV merged bf16 (B*T, 3072). T=2048, H=16, Dh=64. Out bf16 (B*T,1024).
// Block: 256 thr / 4 warps; q-chunk = 128 rows (warp w owns 32). KVBLK=64, nt = 2c+2.
// Grid 512, LPT order (chunk 15 first); bh pinned per XCD. Softmax in exp2 domain.
// V layout Vt[d][k]: u16addr = (d<<6) | ((((k>>3)^(d&7)^(d>>3))&7)<<3) | (k&7)
// (conflict-free for scalar transpose-writes AND ds_read_b128 PV reads).
__global__ __launch_bounds__(256, 4) void attn_kernel(const u16* __restrict__ QKV,
                                                      u16* __restrict__ O) {
  __shared__ __align__(16) u16 Ks[2][4096];  // [64 keys][64 d], swizzled (8KB each)
  __shared__ __align__(16) u16 Vt[2][4096];  // [64 d][64 keys], swizzled (8KB each)
  const int T = 2048, LD = 3072;
  const int blk = blockIdx.x;
  const int xcd = blk & 7;
  const int bh = xcd * 4 + ((blk >> 3) & 3);   // 4 bh per XCD
  const int c = 15 - (blk >> 5);               // LPT: biggest chunks dispatched first
  const int b = bh >> 4, hd = bh & 15;
  const int tid = threadIdx.x;
  const int lane = tid & 63;
  const int w = tid >> 6;                      // 0..3
  const int h = lane >> 5;
  const int qg = c * 128 + w * 32 + (lane & 31);
  const int nt = 2 * c + 2;                    // 64-key tiles

  const u16* Qb = QKV + (size_t)b * T * LD + hd * 64;
  const u16* Kb = Qb + 1024;
  const u16* Vb = Qb + 2048;

  // Q fragments, pre-scaled by 0.125*log2(e)
  const float QSC = 0.18033688011112042f;
  bf16x8 qf[4];
#pragma unroll
  for (int s = 0; s < 4; ++s) {
    bf16x8 raw = *(const bf16x8*)(Qb + (size_t)qg * LD + s * 16 + h * 8);
    union { unsigned wd[4]; bf16x8 v; } u;
#pragma unroll
    for (int e = 0; e < 4; ++e)
      u.wd[e] = cvtpk(bf2f((u16)raw[2 * e]) * QSC, bf2f((u16)raw[2 * e + 1]) * QSC);
    qf[s] = u.v;
  }

  f32x16 oacc[2] = {};
  float m = -INFINITY, l = 0.0f;

  // staging geometry: 512 16B-chunks per tile over 256 threads (2 passes)
  int krow[2], kgc[2], vrow[2], vcol[2];
#pragma unroll
  for (int c2 = 0; c2 < 2; ++c2) {
    int i2 = tid + (c2 << 8);
    krow[c2] = i2 >> 3;                       // 0..63
    kgc[c2] = ((i2 & 7) ^ (krow[c2] & 7)) << 3;
    vrow[c2] = i2 >> 3;                       // key 0..63
    vcol[c2] = i2 & 7;                        // 8-elem d-chunk
  }

#define VWRITE(bb, c2, vvreg) do { \
  _Pragma("unroll") for (int e = 0; e < 8; ++e) { \
    int d = vcol[c2] * 8 + e; \
    Vt[bb][(d << 6) | ((((vrow[c2] >> 3) ^ (d & 7) ^ (d >> 3)) & 7) << 3) | (vrow[c2] & 7)] = (u16)(vvreg)[e]; \
  } \
} while (0)

  // prologue: stage tile 0
#pragma unroll
  for (int c2 = 0; c2 < 2; ++c2) {
    GLOAD16(Kb + (size_t)krow[c2] * LD + kgc[c2], (char*)Ks[0] + (tid + (c2 << 8)) * 16);
    bf16x8 vv0 = *(const bf16x8*)(Vb + (size_t)vrow[c2] * LD + vcol[c2] * 8);
    VWRITE(0, c2, vv0);
  }
  __syncthreads();

  int cur = 0;
  for (int j = 0; j < nt; ++j) {
    const bool pre = (j + 1 < nt);
    bf16x8 vv[2];
    if (pre) {
#pragma unroll
      for (int c2 = 0; c2 < 2; ++c2) {
        GLOAD16(Kb + (size_t)((j + 1) * 64 + krow[c2]) * LD + kgc[c2],
                (char*)Ks[cur ^ 1] + (tid + (c2 << 8)) * 16);
        vv[c2] = *(const bf16x8*)(Vb + (size_t)((j + 1) * 64 + vrow[c2]) * LD + vcol[c2] * 8);
      }
    }

    // S'^T = K * Q'^T : sacc[t] covers keys 64j + 32t .. +32
    f32x16 sacc[2] = {};
    const u16* Kp = Ks[cur];
    __builtin_amdgcn_s_setprio(1);
#pragma unroll
    for (int t = 0; t < 2; ++t) {
#pragma unroll
      for (int s = 0; s < 4; ++s) {
        int row = t * 32 + (lane & 31);
        bf16x8 kf = *(const bf16x8*)(Kp + (row << 6) + ((((2 * s + h) ^ (row & 7)) & 7) << 3));
        sacc[t] = __builtin_amdgcn_mfma_f32_32x32x16_bf16(kf, qf[s], sacc[t], 0, 0, 0);
      }
    }
    __builtin_amdgcn_s_setprio(0);

    if (j >= 2 * c) {  // diagonal tiles: causal mask
#pragma unroll
      for (int t = 0; t < 2; ++t)
#pragma unroll
        for (int r = 0; r < 16; ++r) {
          int key = (j << 6) + 32 * t + (r & 3) + 8 * (r >> 2) + 4 * h;
          if (key > qg) sacc[t][r] = -INFINITY;
        }
    }

    float pmax = -INFINITY;
#pragma unroll
    for (int t = 0; t < 2; ++t)
#pragma unroll
      for (int r = 0; r < 16; ++r) pmax = fmaxf(pmax, sacc[t][r]);
    pmax = fmaxf(pmax, __shfl_xor(pmax, 32, 64));

    // defer-max (log2 domain; bound p <= 2^2.885 = e^2)
    if (!__all(pmax - m <= 2.8853900817779268f)) {
      float mn = fmaxf(m, pmax);
      float alpha = exp2f(m - mn);
      m = mn;
      l *= alpha;
#pragma unroll
      for (int d2 = 0; d2 < 2; ++d2)
#pragma unroll
        for (int r = 0; r < 16; ++r) oacc[d2][r] *= alpha;
    }

    float lsum = 0.0f;
#pragma unroll
    for (int t = 0; t < 2; ++t)
#pragma unroll
      for (int r = 0; r < 16; ++r) {
        float pe = exp2f(sacc[t][r] - m);
        sacc[t][r] = pe;
        lsum += pe;
      }
    lsum += __shfl_xor(lsum, 32, 64);
    l += lsum;

    // P^T B-fragments: pf[2t+kb] holds keys 32t+16kb+8h+0..7 for col q
    union PF { unsigned wd[4]; bf16x8 v; } pf[4];
#pragma unroll
    for (int t = 0; t < 2; ++t) {
#pragma unroll
      for (int kb = 0; kb < 2; ++kb) {
        int base = 8 * kb;
        unsigned A0 = cvtpk(sacc[t][base + 0], sacc[t][base + 1]);
        unsigned A2 = cvtpk(sacc[t][base + 2], sacc[t][base + 3]);
        unsigned A4 = cvtpk(sacc[t][base + 4], sacc[t][base + 5]);
        unsigned A6 = cvtpk(sacc[t][base + 6], sacc[t][base + 7]);
        unsigned S0 = (unsigned)__shfl_xor((int)(h ? A0 : A4), 32, 64);
        unsigned S2 = (unsigned)__shfl_xor((int)(h ? A2 : A6), 32, 64);
        PF& u = pf[2 * t + kb];
        u.wd[0] = h ? S0 : A0;
        u.wd[1] = h ? S2 : A2;
        u.wd[2] = h ? A4 : S0;
        u.wd[3] = h ? A6 : S2;
      }
    }

    // O^T += V^T * P^T
    const u16* Vp = Vt[cur];
    __builtin_amdgcn_s_setprio(1);
#pragma unroll
    for (int d2 = 0; d2 < 2; ++d2) {
      int d = d2 * 32 + (lane & 31);
#pragma unroll
      for (int ks = 0; ks < 4; ++ks) {
        bf16x8 vf = *(const bf16x8*)(Vp + (d << 6) + ((((2 * ks + h) ^ (d & 7) ^ (d >> 3)) & 7) << 3));
        oacc[d2] = __builtin_amdgcn_mfma_f32_32x32x16_bf16(vf, pf[ks].v, oacc[d2], 0, 0, 0);
      }
    }
    __builtin_amdgcn_s_setprio(0);

    // late write of next V tile (loads issued early; latency hidden under compute)
    if (pre) {
#pragma unroll
      for (int c2 = 0; c2 < 2; ++c2) VWRITE(cur ^ 1, c2, vv[c2]);
    }
    __syncthreads();
    cur ^= 1;
  }
#undef VWRITE

  // epilogue: O = O^T / l via LDS transpose (reuse Ks: 16KB), coalesced store
  const float rinv = 1.0f / l;
  u16* Ob = (u16*)Ks;                       // [128 rows][64 d], swizzled
  const int qloc = w * 32 + (lane & 31);    // 0..127
#pragma unroll
  for (int d2 = 0; d2 < 2; ++d2)
#pragma unroll
    for (int r = 0; r < 16; ++r) {
      int d = d2 * 32 + (r & 3) + 8 * (r >> 2) + 4 * h;
      Ob[(qloc << 6) | (d ^ ((qloc & 7) << 3))] = f2bf(oacc[d2][r] * rinv);
    }
  __syncthreads();
#pragma unroll
  for (int it = 0; it < 4; ++it) {
    int r = (tid >> 3) + it * 32;           // 0..127
    int c8 = tid & 7;
    bf16x8 val = *(const bf16x8*)(Ob + (r << 6) + (((c8 ^ (r & 7)) & 7) << 3));
    int qg2 = c * 128 + r;
    *(bf16x8*)(O + (size_t)(b * T + qg2) * 1024 + hd * 64 + c8 * 8) = val;
  }
}

// ---------------- host launch ----------------
extern "C" void kernel_launch(void* const* d_in, const int* in_sizes, int n_in,
                              void* d_out, int out_size, void* d_ws, size_t ws_size,
                              hipStream_t stream) {
  const float* x      = (const float*)d_in[0];
  const float* gamma1 = (const float*)d_in[1];
  const float* beta1  = (const float*)d_in[2];
  const float* Wq     = (const float*)d_in[3];
  const float* bq     = (const float*)d_in[4];
  const float* Wk     = (const float*)d_in[5];
  const float* bk     = (const float*)d_in[6];
  const float* Wv     = (const float*)d_in[7];
  const float* bv     = (const float*)d_in[8];
  const float* Wo     = (const float*)d_in[9];
  const float* bo     = (const float*)d_in[10];
  const float* gamma2 = (const float*)d_in[11];
  const float* beta2  = (const float*)d_in[12];
  const float* W1     = (const float*)d_in[13];
  const float* b1     = (const float*)d_in[14];
  const float* W2     = (const float*)d_in[15];
  const float* b2     = (const float*)d_in[16];

  char* ws = (char*)d_ws;  // 64 MB layout
  u16* WqkvT = (u16*)(ws + 0 * MB);  // 6 MB
  u16* WoT   = (u16*)(ws + 6 * MB);  // 2 MB
  u16* W1T   = (u16*)(ws + 8 * MB);  // 8 MB (4096,1024)
  u16* W2T   = (u16*)(ws + 16 * MB); // 8 MB (1024,4096)
  u16* qkv   = (u16*)(ws + 24 * MB); // 24 MB (4096,3072)
  u16* hb    = (u16*)(ws + 24 * MB); // 32 MB, reuses qkv region after attention
  u16* xn    = (u16*)(ws + 56 * MB); // 8 MB
  float* bqkv = (float*)d_out;
  float* x1 = (float*)d_out;

  const int M = 4096;

  twconv<<<dim3(1024), dim3(256), 0, stream>>>(Wq, WqkvT, 1024, 1024);
  twconv<<<dim3(1024), dim3(256), 0, stream>>>(Wk, WqkvT + 1024 * 1024, 1024, 1024);
  twconv<<<dim3(1024), dim3(256), 0, stream>>>(Wv, WqkvT + 2048 * 1024, 1024, 1024);
  twconv<<<dim3(1024), dim3(256), 0, stream>>>(Wo, WoT, 1024, 1024);
  twconv<<<dim3(4096), dim3(256), 0, stream>>>(W1, W1T, 1024, 4096);
  twconv<<<dim3(4096), dim3(256), 0, stream>>>(W2, W2T, 4096, 1024);
  concat3<<<dim3(4), dim3(256), 0, stream>>>(bq, bk, bv, bqkv, 1024);

  ln_kernel<<<dim3(M), dim3(256), 0, stream>>>(x, gamma1, beta1, xn);

  gemm_bt<0, 128><<<dim3(768), dim3(256), 0, stream>>>(xn, WqkvT, bqkv, nullptr, qkv, M, 3072, 1024);

  attn_kernel<<<dim3(512), dim3(256), 0, stream>>>(qkv, xn);

  gemm_bt<1, 64><<<dim3(512), dim3(256), 0, stream>>>(xn, WoT, bo, x, x1, M, 1024, 1024);

  ln_kernel<<<dim3(M), dim3(256), 0, stream>>>(x1, gamma2, beta2, xn);

  gemm_bt<2, 128><<<dim3(1024), dim3(256), 0, stream>>>(xn, W1T, b1, nullptr, hb, M, 4096, 1024);
  gemm_bt<1, 64><<<dim3(512), dim3(256), 0, stream>>>(hb, W2T, b2, x1, d_out, M, 1024, 4096);
}

// Round 8
// 238.647 us; speedup vs baseline: 1.2804x; 1.2804x over previous
//
#include <hip/hip_runtime.h>
#include <stdint.h>

typedef unsigned short u16;
typedef short bf16x8 __attribute__((ext_vector_type(8)));
typedef float f32x4 __attribute__((ext_vector_type(4)));
typedef float f32x16 __attribute__((ext_vector_type(16)));

#define MB (1024L*1024L)

__device__ inline u16 f2bf(float f) {
  union { float f; unsigned u; } v; v.f = f;
  unsigned r = (v.u + 0x7FFFu + ((v.u >> 16) & 1u)) >> 16;
  return (u16)r;
}

__device__ inline float bf2f(u16 u) {
  union { unsigned u; float f; } v; v.u = ((unsigned)u) << 16; return v.f;
}

__device__ inline unsigned cvtpk(float lo, float hi) {
  unsigned r;
  asm("v_cvt_pk_bf16_f32 %0, %1, %2" : "=v"(r) : "v"(lo), "v"(hi));
  return r;
}

#define GLOAD16(gptr, lptr) \
  __builtin_amdgcn_global_load_lds((__attribute__((address_space(1))) void*)(gptr), \
                                   (__attribute__((address_space(3))) void*)(lptr), 16, 0, 0)

// ---------------- transpose + convert fp32 (K,N) -> bf16 (N,K) ----------------
__global__ __launch_bounds__(256) void twconv(const float* __restrict__ W,
                                              u16* __restrict__ WT, int K, int N) {
  __shared__ float tile[32][33];
  const int nbn = N >> 5;
  const int bk = blockIdx.x / nbn;
  const int bn = blockIdx.x % nbn;
  const int tid = threadIdx.x;
  const int r = tid >> 3;
  const int c4 = (tid & 7) << 2;
  const float4 v = *(const float4*)(W + (size_t)(bk * 32 + r) * N + bn * 32 + c4);
  tile[r][c4 + 0] = v.x; tile[r][c4 + 1] = v.y;
  tile[r][c4 + 2] = v.z; tile[r][c4 + 3] = v.w;
  __syncthreads();
  ushort4 o;
  o.x = f2bf(tile[c4 + 0][r]); o.y = f2bf(tile[c4 + 1][r]);
  o.z = f2bf(tile[c4 + 2][r]); o.w = f2bf(tile[c4 + 3][r]);
  *(ushort4*)(WT + (size_t)(bn * 32 + r) * K + bk * 32 + c4) = o;
}

// ---------------- concat 3 bias vectors ----------------
__global__ __launch_bounds__(256) void concat3(const float* __restrict__ a,
                                               const float* __restrict__ b,
                                               const float* __restrict__ c,
                                               float* __restrict__ out, int n) {
  int i = blockIdx.x * 256 + threadIdx.x;
  if (i < n) { out[i] = a[i]; out[n + i] = b[i]; out[2 * n + i] = c[i]; }
}

// ---------------- LayerNorm fp32 -> bf16, D=1024, one block per row ----------------
__global__ __launch_bounds__(256) void ln_kernel(const float* __restrict__ x,
                                                 const float* __restrict__ gamma,
                                                 const float* __restrict__ beta,
                                                 u16* __restrict__ out) {
  const int row = blockIdx.x;
  const int tid = threadIdx.x;
  const float4 v = *(const float4*)(x + (size_t)row * 1024 + tid * 4);
  float s = v.x + v.y + v.z + v.w;
  float s2 = v.x * v.x + v.y * v.y + v.z * v.z + v.w * v.w;
#pragma unroll
  for (int m = 1; m < 64; m <<= 1) {
    s += __shfl_xor(s, m, 64);
    s2 += __shfl_xor(s2, m, 64);
  }
  __shared__ float red[8];
  const int w = tid >> 6;
  if ((tid & 63) == 0) { red[w] = s; red[4 + w] = s2; }
  __syncthreads();
  s = red[0] + red[1] + red[2] + red[3];
  s2 = red[4] + red[5] + red[6] + red[7];
  const float mean = s * (1.0f / 1024.0f);
  const float var = s2 * (1.0f / 1024.0f) - mean * mean;
  const float rstd = rsqrtf(var + 1e-5f);
  const float4 g = *(const float4*)(gamma + tid * 4);
  const float4 b = *(const float4*)(beta + tid * 4);
  ushort4 o;
  o.x = f2bf(g.x * (v.x - mean) * rstd + b.x);
  o.y = f2bf(g.y * (v.y - mean) * rstd + b.y);
  o.z = f2bf(g.z * (v.z - mean) * rstd + b.z);
  o.w = f2bf(g.w * (v.w - mean) * rstd + b.w);
  *(ushort4*)(out + (size_t)row * 1024 + tid * 4) = o;
}

// ---------------- GEMM: C[M,N] = A[M,K](bf16) @ BT[N,K](bf16)^T ----------------
// BK=64, dbuf, depth-2 prefetch, counted vmcnt, raw barriers, setprio; XCD-swizzled grid.
// Requires M = 4096 (nBM = 32). EPI 0: bf16=acc+bias; 1: f32=acc+bias+res; 2: bf16=gelu.
template <int EPI, int BN>
__global__ __launch_bounds__(256, (BN == 64) ? 3 : 2)
void gemm_bt(const u16* __restrict__ A, const u16* __restrict__ BT,
             const float* __restrict__ bias, const float* __restrict__ res,
             void* __restrict__ outp, int M, int N, int K) {
  constexpr int MF = (BN == 128) ? 4 : 2;
  constexpr int ACH = 4;
  constexpr int BCH = BN / 32;
  constexpr int LOADS = ACH + BCH;
  __shared__ __align__(16) u16 As[2][128 * 64];
  __shared__ __align__(16) u16 Bs[2][BN * 64];
  const int nBN = N / BN;
  const int hw = blockIdx.x;
  const int xcd = hw & 7;
  const int rr = hw >> 3;
  const int bm = xcd * 4 + rr / nBN;
  const int bn = rr % nBN;
  const int tid = threadIdx.x;
  const int lane = tid & 63;
  const int wid = tid >> 6;
  const int wm = (BN == 128) ? (wid >> 1) : wid;
  const int wn = (BN == 128) ? (wid & 1) : 0;
  const int e4 = lane >> 4;

  int abase[MF], ax[MF];
#pragma unroll
  for (int m = 0; m < MF; ++m) {
    int rowa = wm * (MF * 16) + m * 16 + (lane & 15);
    abase[m] = rowa * 64; ax[m] = rowa & 7;
  }
  int bbase[4], bx[4];
#pragma unroll
  for (int n = 0; n < 4; ++n) {
    int rowb = wn * 64 + n * 16 + (lane & 15);
    bbase[n] = rowb * 64; bx[n] = rowb & 7;
  }

  size_t ga[ACH]; int loa[ACH];
#pragma unroll
  for (int c = 0; c < ACH; ++c) {
    int idx = tid + (c << 8);
    int row = idx >> 3;
    int ch = (idx & 7) ^ (row & 7);
    ga[c] = (size_t)(bm * 128 + row) * K + (ch << 3);
    loa[c] = idx << 4;
  }
  size_t gb[BCH]; int lob[BCH];
#pragma unroll
  for (int c = 0; c < BCH; ++c) {
    int idx = tid + (c << 8);
    int row = idx >> 3;
    int ch = (idx & 7) ^ (row & 7);
    gb[c] = (size_t)(bn * BN + row) * K + (ch << 3);
    lob[c] = idx << 4;
  }

#define STAGE_G(t, bb) do { \
  _Pragma("unroll") for (int c = 0; c < ACH; ++c) \
    GLOAD16(A + ga[c] + (size_t)(t) * 64, (char*)As[bb] + loa[c]); \
  _Pragma("unroll") for (int c = 0; c < BCH; ++c) \
    GLOAD16(BT + gb[c] + (size_t)(t) * 64, (char*)Bs[bb] + lob[c]); \
} while (0)

  f32x4 acc[MF][4] = {};
  const int nt = K >> 6;

  STAGE_G(0, 0);
  STAGE_G(1, 1);

  for (int t = 0; t < nt; ++t) {
    if (t + 1 < nt) {
      asm volatile("s_waitcnt vmcnt(%0)" :: "i"(LOADS) : "memory");
    } else {
      asm volatile("s_waitcnt vmcnt(0)" ::: "memory");
    }
    __builtin_amdgcn_s_barrier();          // buf[t&1] published
    const u16* Ap = As[t & 1];
    const u16* Bp = Bs[t & 1];
    bf16x8 af[2][MF], bfr[2][4];
#pragma unroll
    for (int kk = 0; kk < 2; ++kk) {
#pragma unroll
      for (int m = 0; m < MF; ++m)
        af[kk][m] = *(const bf16x8*)(Ap + abase[m] + (((((kk << 2) | e4)) ^ ax[m]) << 3));
#pragma unroll
      for (int n = 0; n < 4; ++n)
        bfr[kk][n] = *(const bf16x8*)(Bp + bbase[n] + (((((kk << 2) | e4)) ^ bx[n]) << 3));
    }
    asm volatile("s_waitcnt lgkmcnt(0)" ::: "memory");
    __builtin_amdgcn_s_barrier();          // all waves done reading buf[t&1]
    if (t + 2 < nt) STAGE_G(t + 2, t & 1);
    __builtin_amdgcn_s_setprio(1);
#pragma unroll
    for (int kk = 0; kk < 2; ++kk)
#pragma unroll
      for (int m = 0; m < MF; ++m)
#pragma unroll
        for (int n = 0; n < 4; ++n)
          acc[m][n] = __builtin_amdgcn_mfma_f32_16x16x32_bf16(af[kk][m], bfr[kk][n], acc[m][n], 0, 0, 0);
    __builtin_amdgcn_s_setprio(0);
  }
#undef STAGE_G

  const int rbase = bm * 128 + wm * (MF * 16);
  const int cbase = bn * BN + wn * 64;
#pragma unroll
  for (int m = 0; m < MF; ++m) {
#pragma unroll
    for (int n = 0; n < 4; ++n) {
      const int col = cbase + n * 16 + (lane & 15);
      const int row0 = rbase + m * 16 + ((lane >> 4) << 2);
      const float bv = bias[col];
#pragma unroll
      for (int r = 0; r < 4; ++r) {
        const int row = row0 + r;
        float v = acc[m][n][r] + bv;
        if (EPI == 1) {
          ((float*)outp)[(size_t)row * N + col] = v + res[(size_t)row * N + col];
        } else if (EPI == 2) {
          float tt = v * (1.0f + 0.044715f * v * v);
          float sg = 1.0f / (1.0f + __expf(-1.5957691216057308f * tt));
          ((u16*)outp)[(size_t)row * N + col] = f2bf(v * sg);
        } else {
          ((u16*)outp)[(size_t)row * N + col] = f2bf(v);
        }
      }
    }
  }
}

// ---------------- causal flash attention, 8-warp 32x32 swapped structure ----------------
// QKV merged bf16 (B*T, 3072). T=2048, H=16, Dh=64. Out bf16 (B*T,1024).
// Block: 512 thr; warps 0-3 -> 128-row chunk cA=p, warps 4-7 -> cB=15-p. Grid 256,
// XCD-pinned: bh = xcd*4 + ((blk>>3)&3) keeps each (b,h)'s K/V in one XCD's L2.
// Q pre-scaled by 0.125*log2(e): softmax in exp2 domain. setprio on MFMA clusters.
__global__ __launch_bounds__(512, 2) void attn_kernel(const u16* __restrict__ QKV,
                                                      u16* __restrict__ O) {
  __shared__ __align__(16) u16 KV[4][4096];  // K0,K1,V0,V1 (8KB each); epilogue reuse
  const int T = 2048, LD = 3072;
  const int blk = blockIdx.x;
  const int xcd = blk & 7;
  const int i = blk >> 3;                 // 0..31
  const int bh = xcd * 4 + (i & 3);       // 4 bh per XCD
  const int p = i >> 2;                   // 0..7
  const int b = bh >> 4, hd = bh & 15;
  const int tid = threadIdx.x;
  const int lane = tid & 63;
  const int w = tid >> 6;
  const int h = lane >> 5;
  const int cA = p, cB = 15 - p;
  const int myc = (w < 4) ? cA : cB;
  const int qwb = myc * 128 + (w & 3) * 32;
  const int qg = qwb + (lane & 31);
  const int diag = qwb >> 6;
  const int myNt = diag + 1;
  const int nt = 2 * cB + 2;

  const u16* Qb = QKV + (size_t)b * T * LD + hd * 64;
  const u16* Kb = Qb + 1024;
  const u16* Vb = Qb + 2048;

  // Q fragments, pre-scaled by 0.125*log2(e)
  const float QSC = 0.18033688011112042f;
  bf16x8 qf[4];
#pragma unroll
  for (int s = 0; s < 4; ++s) {
    bf16x8 raw = *(const bf16x8*)(Qb + (size_t)qg * LD + s * 16 + h * 8);
    union { unsigned wd[4]; bf16x8 v; } u;
#pragma unroll
    for (int e = 0; e < 4; ++e)
      u.wd[e] = cvtpk(bf2f((u16)raw[2 * e]) * QSC, bf2f((u16)raw[2 * e + 1]) * QSC);
    qf[s] = u.v;
  }

  f32x16 oacc[2] = {};
  float m = -INFINITY, l = 0.0f;

  // staging geometry (512 threads: 1x 16B K gload + 1x bf16x8 V reg load each)
  const int srow = tid >> 3;      // 0..63
  const int scol = tid & 7;       // 16B chunk
  const int kgc = ((scol ^ (srow & 7)) << 3);

  // prologue: stage tile 0
  GLOAD16(Kb + (size_t)srow * LD + kgc, (char*)KV[0] + tid * 16);
  {
    bf16x8 vv0 = *(const bf16x8*)(Vb + (size_t)srow * LD + scol * 8);
#pragma unroll
    for (int e = 0; e < 8; ++e) {
      int d = scol * 8 + e;
      KV[2][(d << 6) | (srow & 7) | ((((srow >> 3) ^ e ^ scol) & 7) << 3)] = (u16)vv0[e];
    }
  }
  __syncthreads();

  int cur = 0;
  for (int j = 0; j < nt; ++j) {
    const bool pre = (j + 1 < nt);
    bf16x8 vv;
    if (pre) {
      GLOAD16(Kb + (size_t)((j + 1) * 64 + srow) * LD + kgc, (char*)KV[cur ^ 1] + tid * 16);
      vv = *(const bf16x8*)(Vb + (size_t)((j + 1) * 64 + srow) * LD + scol * 8);
    }

    if (j < myNt) {
      // S'^T = K * Q'^T (log2-domain scores)
      f32x16 sacc[2] = {};
      const u16* Kp = KV[cur];
      __builtin_amdgcn_s_setprio(1);
#pragma unroll
      for (int t = 0; t < 2; ++t) {
#pragma unroll
        for (int s = 0; s < 4; ++s) {
          int row = t * 32 + (lane & 31);
          bf16x8 kf = *(const bf16x8*)(Kp + (row << 6) + ((((2 * s + h) ^ (row & 7)) & 7) << 3));
          sacc[t] = __builtin_amdgcn_mfma_f32_32x32x16_bf16(kf, qf[s], sacc[t], 0, 0, 0);
        }
      }
      __builtin_amdgcn_s_setprio(0);

      if (j == diag) {
#pragma unroll
        for (int t = 0; t < 2; ++t)
#pragma unroll
          for (int r = 0; r < 16; ++r) {
            int key = (j << 6) + 32 * t + (r & 3) + 8 * (r >> 2) + 4 * h;
            if (key > qg) sacc[t][r] = -INFINITY;
          }
      }

      float pmax = -INFINITY;
#pragma unroll
      for (int t = 0; t < 2; ++t)
#pragma unroll
        for (int r = 0; r < 16; ++r) pmax = fmaxf(pmax, sacc[t][r]);
      pmax = fmaxf(pmax, __shfl_xor(pmax, 32, 64));

      // defer-max (log2 domain; bound p <= 2^2.885 = e^2)
      if (!__all(pmax - m <= 2.8853900817779268f)) {
        float mn = fmaxf(m, pmax);
        float alpha = exp2f(m - mn);
        m = mn;
        l *= alpha;
#pragma unroll
        for (int d2 = 0; d2 < 2; ++d2)
#pragma unroll
          for (int r = 0; r < 16; ++r) oacc[d2][r] *= alpha;
      }

      float lsum = 0.0f;
#pragma unroll
      for (int t = 0; t < 2; ++t)
#pragma unroll
        for (int r = 0; r < 16; ++r) {
          float pe = exp2f(sacc[t][r] - m);
          sacc[t][r] = pe;
          lsum += pe;
        }
      lsum += __shfl_xor(lsum, 32, 64);
      l += lsum;

      // P^T B-fragments (cvt_pk + half swap)
      union PF { unsigned wd[4]; bf16x8 v; } pf[4];
#pragma unroll
      for (int t = 0; t < 2; ++t) {
#pragma unroll
        for (int kb = 0; kb < 2; ++kb) {
          int base = 8 * kb;
          unsigned A0 = cvtpk(sacc[t][base + 0], sacc[t][base + 1]);
          unsigned A2 = cvtpk(sacc[t][base + 2], sacc[t][base + 3]);
          unsigned A4 = cvtpk(sacc[t][base + 4], sacc[t][base + 5]);
          unsigned A6 = cvtpk(sacc[t][base + 6], sacc[t][base + 7]);
          unsigned S0 = (unsigned)__shfl_xor((int)(h ? A0 : A4), 32, 64);
          unsigned S2 = (unsigned)__shfl_xor((int)(h ? A2 : A6), 32, 64);
          PF& u = pf[2 * t + kb];
          u.wd[0] = h ? S0 : A0;
          u.wd[1] = h ? S2 : A2;
          u.wd[2] = h ? A4 : S0;
          u.wd[3] = h ? A6 : S2;
        }
      }

      // O^T += V^T * P^T
      const u16* Vp = KV[2 + cur];
      __builtin_amdgcn_s_setprio(1);
#pragma unroll
      for (int d2 = 0; d2 < 2; ++d2) {
        int d = d2 * 32 + (lane & 31);
#pragma unroll
        for (int ks = 0; ks < 4; ++ks) {
          bf16x8 vf = *(const bf16x8*)(Vp + (d << 6) + ((((2 * ks + h) ^ (d & 7) ^ ((d >> 3) & 7)) & 7) << 3));
          oacc[d2] = __builtin_amdgcn_mfma_f32_32x32x16_bf16(vf, pf[ks].v, oacc[d2], 0, 0, 0);
        }
      }
      __builtin_amdgcn_s_setprio(0);
    }

    // late write of next V tile (load issued early; hides HBM/L2 latency under compute)
    if (pre) {
#pragma unroll
      for (int e = 0; e < 8; ++e) {
        int d = scol * 8 + e;
        KV[2 + (cur ^ 1)][(d << 6) | (srow & 7) | ((((srow >> 3) ^ e ^ scol) & 7) << 3)] = (u16)vv[e];
      }
    }
    __syncthreads();
    cur ^= 1;
  }

  // epilogue: O = O^T / l, transpose via LDS, coalesced store
  const float rinv = 1.0f / l;
  u16* Ob = (u16*)KV;
  const int qloc = w * 32 + (lane & 31);
#pragma unroll
  for (int d2 = 0; d2 < 2; ++d2)
#pragma unroll
    for (int r = 0; r < 16; ++r) {
      int d = d2 * 32 + (r & 3) + 8 * (r >> 2) + 4 * h;
      Ob[(qloc << 6) | (d ^ ((qloc & 7) << 3))] = f2bf(oacc[d2][r] * rinv);
    }
  __syncthreads();
#pragma unroll
  for (int it = 0; it < 4; ++it) {
    int r = (tid >> 3) + it * 64;
    int c = tid & 7;
    bf16x8 val = *(const bf16x8*)(Ob + (r << 6) + (((c ^ (r & 7)) & 7) << 3));
    int qg2 = (r < 128) ? (cA * 128 + r) : (cB * 128 + (r - 128));
    *(bf16x8*)(O + (size_t)(b * T + qg2) * 1024 + hd * 64 + c * 8) = val;
  }
}

// ---------------- host launch ----------------
extern "C" void kernel_launch(void* const* d_in, const int* in_sizes, int n_in,
                              void* d_out, int out_size, void* d_ws, size_t ws_size,
                              hipStream_t stream) {
  const float* x      = (const float*)d_in[0];
  const float* gamma1 = (const float*)d_in[1];
  const float* beta1  = (const float*)d_in[2];
  const float* Wq     = (const float*)d_in[3];
  const float* bq     = (const float*)d_in[4];
  const float* Wk     = (const float*)d_in[5];
  const float* bk     = (const float*)d_in[6];
  const float* Wv     = (const float*)d_in[7];
  const float* bv     = (const float*)d_in[8];
  const float* Wo     = (const float*)d_in[9];
  const float* bo     = (const float*)d_in[10];
  const float* gamma2 = (const float*)d_in[11];
  const float* beta2  = (const float*)d_in[12];
  const float* W1     = (const float*)d_in[13];
  const float* b1     = (const float*)d_in[14];
  const float* W2     = (const float*)d_in[15];
  const float* b2     = (const float*)d_in[16];

  char* ws = (char*)d_ws;  // 64 MB layout
  u16* WqkvT = (u16*)(ws + 0 * MB);  // 6 MB
  u16* WoT   = (u16*)(ws + 6 * MB);  // 2 MB
  u16* W1T   = (u16*)(ws + 8 * MB);  // 8 MB (4096,1024)
  u16* W2T   = (u16*)(ws + 16 * MB); // 8 MB (1024,4096)
  u16* qkv   = (u16*)(ws + 24 * MB); // 24 MB (4096,3072)
  u16* hb    = (u16*)(ws + 24 * MB); // 32 MB, reuses qkv region after attention
  u16* xn    = (u16*)(ws + 56 * MB); // 8 MB
  float* bqkv = (float*)d_out;
  float* x1 = (float*)d_out;

  const int M = 4096;

  twconv<<<dim3(1024), dim3(256), 0, stream>>>(Wq, WqkvT, 1024, 1024);
  twconv<<<dim3(1024), dim3(256), 0, stream>>>(Wk, WqkvT + 1024 * 1024, 1024, 1024);
  twconv<<<dim3(1024), dim3(256), 0, stream>>>(Wv, WqkvT + 2048 * 1024, 1024, 1024);
  twconv<<<dim3(1024), dim3(256), 0, stream>>>(Wo, WoT, 1024, 1024);
  twconv<<<dim3(4096), dim3(256), 0, stream>>>(W1, W1T, 1024, 4096);
  twconv<<<dim3(4096), dim3(256), 0, stream>>>(W2, W2T, 4096, 1024);
  concat3<<<dim3(4), dim3(256), 0, stream>>>(bq, bk, bv, bqkv, 1024);

  ln_kernel<<<dim3(M), dim3(256), 0, stream>>>(x, gamma1, beta1, xn);

  gemm_bt<0, 128><<<dim3(768), dim3(256), 0, stream>>>(xn, WqkvT, bqkv, nullptr, qkv, M, 3072, 1024);

  attn_kernel<<<dim3(256), dim3(512), 0, stream>>>(qkv, xn);

  gemm_bt<1, 64><<<dim3(512), dim3(256), 0, stream>>>(xn, WoT, bo, x, x1, M, 1024, 1024);

  ln_kernel<<<dim3(M), dim3(256), 0, stream>>>(x1, gamma2, beta2, xn);

  gemm_bt<2, 128><<<dim3(1024), dim3(256), 0, stream>>>(xn, W1T, b1, nullptr, hb, M, 4096, 1024);
  gemm_bt<1, 64><<<dim3(512), dim3(256), 0, stream>>>(hb, W2T, b2, x1, d_out, M, 1024, 4096);
}